// Round 6
// baseline (217.544 us; speedup 1.0000x reference)
//
#include <hip/hip_runtime.h>
#include <cstdint>
#include <cstddef>

#define SEQL   2048
#define DMODEL 1024
#define NHEADS 16
#define DHEAD  64
#define MROWS  4096   // BATCH * SEQ

typedef __attribute__((ext_vector_type(8))) short short8;   // 8 bf16 (4 VGPRs)
typedef __attribute__((ext_vector_type(4))) float f32x4;    // MFMA 16x16 C/D
typedef __attribute__((ext_vector_type(4))) unsigned int u32x4;

__device__ __forceinline__ unsigned short f2bf(float x) {
  unsigned int u = __float_as_uint(x);
  u += 0x7fffu + ((u >> 16) & 1u);   // round-to-nearest-even
  return (unsigned short)(u >> 16);
}
__device__ __forceinline__ float bf2f(unsigned short u) {
  return __uint_as_float(((unsigned int)u) << 16);
}
// pack two f32 -> 2xbf16 in one VGPR (RNE); no builtin on gfx950 -> asm
__device__ __forceinline__ unsigned int cvtpk(float lo, float hi) {
  unsigned int r;
  asm("v_cvt_pk_bf16_f32 %0, %1, %2" : "=v"(r) : "v"(lo), "v"(hi));
  return r;
}
// load 8 contiguous fp32, round to 8 bf16
__device__ __forceinline__ short8 cvt8(const float* __restrict__ p) {
  const float4 lo = *(const float4*)p;
  const float4 hi = *(const float4*)(p + 4);
  short8 v;
  v[0] = (short)f2bf(lo.x); v[1] = (short)f2bf(lo.y);
  v[2] = (short)f2bf(lo.z); v[3] = (short)f2bf(lo.w);
  v[4] = (short)f2bf(hi.x); v[5] = (short)f2bf(hi.y);
  v[6] = (short)f2bf(hi.z); v[7] = (short)f2bf(hi.w);
  return v;
}
// async global->LDS, 16B per lane; lds base must be wave-uniform
__device__ __forceinline__ void gload_lds16(const unsigned short* g, unsigned short* l) {
  __builtin_amdgcn_global_load_lds(
      (const __attribute__((address_space(1))) unsigned int*)g,
      (__attribute__((address_space(3))) unsigned int*)l, 16, 0, 0);
}

// ---------------------------------------------------------------------------
// One-shot fp32 -> bf16 conversion of x and the four weight matrices.
// ---------------------------------------------------------------------------
__global__ __launch_bounds__(256) void cvt_bf16(
    const float* __restrict__ x,  const float* __restrict__ wq,
    const float* __restrict__ wk, const float* __restrict__ wv,
    const float* __restrict__ wo,
    unsigned short* __restrict__ xb,  unsigned short* __restrict__ wqb,
    unsigned short* __restrict__ wkb, unsigned short* __restrict__ wvb,
    unsigned short* __restrict__ wob) {
  const int y = blockIdx.y;
  const float* src; unsigned short* dst;
  if (y < 4)       { src = x + ((size_t)y << 20); dst = xb + ((size_t)y << 20); }
  else if (y == 4) { src = wq; dst = wqb; }
  else if (y == 5) { src = wk; dst = wkb; }
  else if (y == 6) { src = wv; dst = wvb; }
  else             { src = wo; dst = wob; }
  const size_t i = ((size_t)blockIdx.x * 256 + threadIdx.x) * 8;
  *(short8*)(dst + i) = cvt8(src + i);
}

// ---------------------------------------------------------------------------
// QKV projection, all-bf16, async staging (m97-style).
// z=0 -> Q bf16; z=1 -> K bf16; z=2 -> V transposed into Vt.
// ---------------------------------------------------------------------------
__global__ __launch_bounds__(256) void gemm_qkv(
    const unsigned short* __restrict__ A,
    const unsigned short* __restrict__ W0, const unsigned short* __restrict__ W1,
    const unsigned short* __restrict__ W2,
    unsigned short* __restrict__ C0, unsigned short* __restrict__ C1,
    unsigned short* __restrict__ Vt,
    int Mda, int Nda, int Kda) {
  const unsigned short* W;
  if (blockIdx.z == 0)      W = W0;
  else if (blockIdx.z == 1) W = W1;
  else                      W = W2;

  __shared__ __attribute__((aligned(16))) unsigned short As[128 * 32];
  __shared__ __attribute__((aligned(16))) unsigned short Bs[128 * 32];

  const int t = threadIdx.x;
  const int m0 = blockIdx.y * 128, n0 = blockIdx.x * 128;
  const int w = t >> 6, lane = t & 63;
  const int l15 = lane & 15, quad = lane >> 4;
  const int wm = (w >> 1) * 64, wn = (w & 1) * 64;

  const int r1 = t >> 2,         c1 = (t & 3) * 8;
  const int r2 = (t + 256) >> 2, c2 = (t & 3) * 8;
  unsigned short* asd1 = As + (size_t)(w << 6) * 8;
  unsigned short* asd2 = As + (size_t)(256 + (w << 6)) * 8;
  unsigned short* bsd1 = Bs + (size_t)(w << 6) * 8;
  unsigned short* bsd2 = Bs + (size_t)(256 + (w << 6)) * 8;

  f32x4 acc[4][4] = {};

  for (int k0 = 0; k0 < Kda; k0 += 32) {
    __syncthreads();
    gload_lds16(A + (size_t)(m0 + r1) * Kda + k0 + c1, asd1);
    gload_lds16(A + (size_t)(m0 + r2) * Kda + k0 + c2, asd2);
    gload_lds16(W + (size_t)(n0 + r1) * Kda + k0 + c1, bsd1);
    gload_lds16(W + (size_t)(n0 + r2) * Kda + k0 + c2, bsd2);
    __syncthreads();

    short8 af[4], bfr[4];
#pragma unroll
    for (int i = 0; i < 4; ++i)
      af[i] = *(const short8*)(&As[(wm + i * 16 + l15) * 32 + quad * 8]);
#pragma unroll
    for (int j = 0; j < 4; ++j)
      bfr[j] = *(const short8*)(&Bs[(wn + j * 16 + l15) * 32 + quad * 8]);
#pragma unroll
    for (int i = 0; i < 4; ++i)
#pragma unroll
      for (int j = 0; j < 4; ++j)
        acc[i][j] = __builtin_amdgcn_mfma_f32_16x16x32_bf16(af[i], bfr[j], acc[i][j], 0, 0, 0);
  }

  if (blockIdx.z != 2) {
    unsigned short* C = (blockIdx.z == 0) ? C0 : C1;
#pragma unroll
    for (int i = 0; i < 4; ++i)
#pragma unroll
      for (int j = 0; j < 4; ++j)
#pragma unroll
        for (int r = 0; r < 4; ++r) {
          int row = m0 + wm + i * 16 + quad * 4 + r;
          int col = n0 + wn + j * 16 + l15;
          C[(size_t)row * Nda + col] = f2bf(acc[i][j][r]);
        }
  } else {
    // V transposed write: 4 consecutive s-values per 8B store
#pragma unroll
    for (int i = 0; i < 4; ++i) {
      const int srow = m0 + wm + i * 16 + quad * 4;   // b*SEQL + s (s%4==0)
      const int bq = srow >> 11, s = srow & (SEQL - 1);
#pragma unroll
      for (int j = 0; j < 4; ++j) {
        const int col = n0 + wn + j * 16 + l15;       // h*64 + d
        ushort4 v;
        v.x = f2bf(acc[i][j][0]); v.y = f2bf(acc[i][j][1]);
        v.z = f2bf(acc[i][j][2]); v.w = f2bf(acc[i][j][3]);
        *(ushort4*)(Vt + ((size_t)(bq * DMODEL + col)) * SEQL + s) = v;
      }
    }
  }
}

// ---------------------------------------------------------------------------
// Output projection: A bf16 [M][K], W bf16 [N][K], C fp32 [M][N]
// ---------------------------------------------------------------------------
__global__ __launch_bounds__(256) void gemm_out(
    const unsigned short* __restrict__ A,
    const unsigned short* __restrict__ W,
    float* __restrict__ C,
    int Mda, int Nda, int Kda) {
  __shared__ __attribute__((aligned(16))) unsigned short As[128 * 32];
  __shared__ __attribute__((aligned(16))) unsigned short Bs[128 * 32];

  const int t = threadIdx.x;
  const int m0 = blockIdx.y * 128, n0 = blockIdx.x * 128;
  const int w = t >> 6, lane = t & 63;
  const int l15 = lane & 15, quad = lane >> 4;
  const int wm = (w >> 1) * 64, wn = (w & 1) * 64;

  const int r1 = t >> 2,         c1 = (t & 3) * 8;
  const int r2 = (t + 256) >> 2, c2 = (t & 3) * 8;
  unsigned short* asd1 = As + (size_t)(w << 6) * 8;
  unsigned short* asd2 = As + (size_t)(256 + (w << 6)) * 8;
  unsigned short* bsd1 = Bs + (size_t)(w << 6) * 8;
  unsigned short* bsd2 = Bs + (size_t)(256 + (w << 6)) * 8;

  f32x4 acc[4][4] = {};

  for (int k0 = 0; k0 < Kda; k0 += 32) {
    __syncthreads();
    gload_lds16(A + (size_t)(m0 + r1) * Kda + k0 + c1, asd1);
    gload_lds16(A + (size_t)(m0 + r2) * Kda + k0 + c2, asd2);
    gload_lds16(W + (size_t)(n0 + r1) * Kda + k0 + c1, bsd1);
    gload_lds16(W + (size_t)(n0 + r2) * Kda + k0 + c2, bsd2);
    __syncthreads();

    short8 af[4], bfr[4];
#pragma unroll
    for (int i = 0; i < 4; ++i)
      af[i] = *(const short8*)(&As[(wm + i * 16 + l15) * 32 + quad * 8]);
#pragma unroll
    for (int j = 0; j < 4; ++j)
      bfr[j] = *(const short8*)(&Bs[(wn + j * 16 + l15) * 32 + quad * 8]);
#pragma unroll
    for (int i = 0; i < 4; ++i)
#pragma unroll
      for (int j = 0; j < 4; ++j)
        acc[i][j] = __builtin_amdgcn_mfma_f32_16x16x32_bf16(af[i], bfr[j], acc[i][j], 0, 0, 0);
  }

#pragma unroll
  for (int i = 0; i < 4; ++i)
#pragma unroll
    for (int j = 0; j < 4; ++j)
#pragma unroll
      for (int r = 0; r < 4; ++r) {
        int row = m0 + wm + i * 16 + quad * 4 + r;
        int col = n0 + wn + j * 16 + l15;
        C[(size_t)row * Nda + col] = acc[i][j][r];
      }
}

// ---------------------------------------------------------------------------
// In-place RoPE on bf16 Q and K flat [M][1024].
// Q additionally pre-scaled by 1/sqrt(DHEAD)=0.125 (exact in bf16).
// ---------------------------------------------------------------------------
__global__ __launch_bounds__(256) void rope_inplace(unsigned short* __restrict__ Q,
                                                    unsigned short* __restrict__ K,
                                                    const int* __restrict__ pos_arr) {
  const int row = blockIdx.x;            // b*SEQ + s
  const int s = row & (SEQL - 1);
  const float pos = (float)pos_arr[s];
  // log2(10000)/32 = 0.4152410118609203
  for (int p = threadIdx.x; p < 512; p += 256) {
    const int h = p >> 5, i = p & 31;
    float inv = exp2f((float)i * -0.4152410118609203f);
    float ang = pos * inv;
    float sn, cs;
    sincosf(ang, &sn, &cs);
    size_t base = (size_t)row * DMODEL + h * DHEAD + 2 * i;
    float e = bf2f(Q[base]), o = bf2f(Q[base + 1]);
    Q[base]     = f2bf((e * cs - o * sn) * 0.125f);
    Q[base + 1] = f2bf((e * sn + o * cs) * 0.125f);
    e = bf2f(K[base]); o = bf2f(K[base + 1]);
    K[base]     = f2bf(e * cs - o * sn);
    K[base + 1] = f2bf(e * sn + o * cs);
  }
}

// exp + causal-mask + bf16-pack for one 16-q group over this kv64 tile.
// Produces bp0 (kv +0/+4 slices) and bp1 (kv +32/+36 slices), accumulates lp.
#define EXP_PACK(S1, S2, S3, S4, QW, QROW, BP0, BP1, LP)                      \
  {                                                                           \
    float p1[4], p2[4], p3[4], p4[4];                                         \
    if (kv0 + 63 <= (QW)) {                                                   \
      _Pragma("unroll") for (int r = 0; r < 4; ++r) {                         \
        p1[r] = __expf(S1[r]); p2[r] = __expf(S2[r]);                         \
        p3[r] = __expf(S3[r]); p4[r] = __expf(S4[r]);                         \
        LP += (p1[r] + p2[r]) + (p3[r] + p4[r]);                              \
      }                                                                       \
    } else {                                                                  \
      _Pragma("unroll") for (int r = 0; r < 4; ++r) {                         \
        const int kv1 = kv0 + 8 * quad + r;                                   \
        p1[r] = (kv1 > (QROW))      ? 0.f : __expf(S1[r]);                    \
        p2[r] = (kv1 + 4 > (QROW))  ? 0.f : __expf(S2[r]);                    \
        p3[r] = (kv1 + 32 > (QROW)) ? 0.f : __expf(S3[r]);                    \
        p4[r] = (kv1 + 36 > (QROW)) ? 0.f : __expf(S4[r]);                    \
        LP += (p1[r] + p2[r]) + (p3[r] + p4[r]);                              \
      }                                                                       \
    }                                                                         \
    u32x4 lo_, hi_;                                                           \
    lo_[0] = cvtpk(p1[0], p1[1]); lo_[1] = cvtpk(p1[2], p1[3]);               \
    lo_[2] = cvtpk(p2[0], p2[1]); lo_[3] = cvtpk(p2[2], p2[3]);               \
    hi_[0] = cvtpk(p3[0], p3[1]); hi_[1] = cvtpk(p3[2], p3[3]);               \
    hi_[2] = cvtpk(p4[0], p4[1]); hi_[3] = cvtpk(p4[2], p4[3]);               \
    BP0 = __builtin_bit_cast(short8, lo_);                                    \
    BP1 = __builtin_bit_cast(short8, hi_);                                    \
  }

// K fragment offsets (shorts): frag jj at (jj>>1)*4*DMODEL + (jj&1)*32,
// second kv-half (+32 kv rows) at +32*DMODEL.  V frag jj at jj*16*SEQL,
// second half at +32.  Derived from the staging permutation gg=jj*64+lane:
// ktau=jj>>1, kseg=quad+4*(jj&1), km=l15; vdb=jj, vq=quad, vm=l15.
#define KO(jj) ((size_t)((jj) >> 1) * 4 * DMODEL + ((jj) & 1) * 32)
#define VO(jj) ((size_t)(jj) * 16 * SEQL)

// ---------------------------------------------------------------------------
// Causal attention R16b: BARRIER-FREE main loop (R16 resubmit; infra failed).
//  R12-R15 post-mortem: every throughput resource ruled out (MFMA 13%, VALU
//  21-30%, LDS <=53%, HBM 5%); bottleneck is the barrier-lockstepped per-trip
//  dependency chain. Fix: remove LDS staging + ALL main-loop barriers.
//  - K/V are L2-resident (2MB/XCD); each wave reads its kv stripe DIRECTLY
//    from global per-lane (addresses = the proven staging permutation,
//    collapsed to ONE base pointer + compile-time offsets per operand).
//  - Wave w handles kv tiles t === w (mod 4) for ALL 64 q rows of the block
//    (4 q-groups): tile read exactly once per block (same L2 traffic as
//    staged), 4 MFMA per load (in-wave reuse replaces cross-wave reuse).
//  - Waves fully independent; V loads issue early, K reloaded post-QK^T.
//  - One cross-wave combine per phase (disjoint kv stripes -> f32 add) via
//    48KB LDS + 2 barriers.  Pairing (qblk p then 31-p) kept for balance.
// ---------------------------------------------------------------------------
__global__ __launch_bounds__(256, 2) void attn_kernel(const unsigned short* __restrict__ Kf,
                                                      const unsigned short* __restrict__ Vt,
                                                      unsigned short* __restrict__ Qio) {
  // combine scratch: [dest group][src-wave idx 0..2][db][quad][l15] x f32x4
  __shared__ __attribute__((aligned(16))) float Osum[4][3][4][4][16][4];  // 48 KB
  __shared__ float Lsum[4][3][16];                                        // 768 B

  const int id = blockIdx.x;                    // id = grp*128 + qpair*8 + xcd
  const int bh = ((id >> 7) << 3) | (id & 7);   // grp*8 + xcd (L2 locality)
  const int qpair = (id >> 3) & 15;             // 0..15
  const int b = bh >> 4, h = bh & 15;
  const int w = threadIdx.x >> 6;
  const int lane = threadIdx.x & 63;
  const int l15 = lane & 15, quad = lane >> 4;

  // single-base per-lane K/V addressing (see KO/VO derivation above)
  const int kvl0 = 8 * (l15 >> 2) + (l15 & 3);
  const unsigned short* kbase0 =
      Kf + ((size_t)(b * SEQL + kvl0)) * DMODEL + h * DHEAD + quad * 8;
  const unsigned short* vbase0 =
      Vt + ((size_t)(bh * DHEAD + l15)) * SEQL + quad * 8;

#pragma unroll 1
  for (int phase = 0; phase < 2; ++phase) {
    const int qblk = (phase == 0) ? qpair : 31 - qpair;
    const int Q0 = qblk << 6;                   // block covers q rows Q0..Q0+63

    // Q B-frags for all 4 q-groups: n=l15 (q), k=8*quad+j (d)
    short8 bq[4][2];
#pragma unroll
    for (int g = 0; g < 4; ++g) {
      const unsigned short* qp =
          Qio + ((size_t)(b * SEQL + Q0 + g * 16 + l15)) * DMODEL + h * DHEAD + quad * 8;
      bq[g][0] = *(const short8*)(qp);
      bq[g][1] = *(const short8*)(qp + 32);
    }

    f32x4 oacc[4][4] = {};   // [group][d-block]
    float lp[4] = {0.f, 0.f, 0.f, 0.f};

    // wave's kv stripe: tiles t = w, w+4, ... <= qblk
    const int nt = (qblk >= w) ? ((qblk - w) >> 2) + 1 : 0;
    const unsigned short* kp = kbase0 + (size_t)(w * 64) * DMODEL;
    const unsigned short* vp = vbase0 + w * 64;

    short8 kc[8];
    if (nt > 0) {
#pragma unroll
      for (int jj = 0; jj < 4; ++jj) {
        kc[jj]     = *(const short8*)(kp + KO(jj));
        kc[jj + 4] = *(const short8*)(kp + KO(jj) + 32 * DMODEL);
      }
      kp += (size_t)256 * DMODEL;
    }

    int kv0 = w * 64;
#pragma unroll 1
    for (int it = 0; it < nt; ++it) {
      // V loads for this tile (used at PV, well after issue)
      short8 vc[8];
#pragma unroll
      for (int jj = 0; jj < 4; ++jj) {
        vc[jj]     = *(const short8*)(vp + VO(jj));
        vc[jj + 4] = *(const short8*)(vp + VO(jj) + 32);
      }
      vp += 256;

      // QK^T + exp per q-group (kc reused by all 4 groups)
      short8 bp[4][2];
      const f32x4 z = {0.f, 0.f, 0.f, 0.f};
      __builtin_amdgcn_s_setprio(1);
#pragma unroll
      for (int g = 0; g < 4; ++g) {
        const int qw_g = Q0 + g * 16;
        const int qrow_g = qw_g + l15;
        f32x4 s1 = __builtin_amdgcn_mfma_f32_16x16x32_bf16(kc[0], bq[g][0], z, 0, 0, 0);
        s1 = __builtin_amdgcn_mfma_f32_16x16x32_bf16(kc[1], bq[g][1], s1, 0, 0, 0);
        f32x4 s2 = __builtin_amdgcn_mfma_f32_16x16x32_bf16(kc[2], bq[g][0], z, 0, 0, 0);
        s2 = __builtin_amdgcn_mfma_f32_16x16x32_bf16(kc[3], bq[g][1], s2, 0, 0, 0);
        f32x4 s3 = __builtin_amdgcn_mfma_f32_16x16x32_bf16(kc[4], bq[g][0], z, 0, 0, 0);
        s3 = __builtin_amdgcn_mfma_f32_16x16x32_bf16(kc[5], bq[g][1], s3, 0, 0, 0);
        f32x4 s4 = __builtin_amdgcn_mfma_f32_16x16x32_bf16(kc[6], bq[g][0], z, 0, 0, 0);
        s4 = __builtin_amdgcn_mfma_f32_16x16x32_bf16(kc[7], bq[g][1], s4, 0, 0, 0);
        EXP_PACK(s1, s2, s3, s4, qw_g, qrow_g, bp[g][0], bp[g][1], lp[g]);
      }
      __builtin_amdgcn_s_setprio(0);

      // reload kc with next tile (kc dead after QK^T g=3; used next iter)
      if (it + 1 < nt) {
#pragma unroll
        for (int jj = 0; jj < 4; ++jj) {
          kc[jj]     = *(const short8*)(kp + KO(jj));
          kc[jj + 4] = *(const short8*)(kp + KO(jj) + 32 * DMODEL);
        }
        kp += (size_t)256 * DMODEL;
      }

      // PV: vc reused by all 4 groups
      __builtin_amdgcn_s_setprio(1);
#pragma unroll
      for (int g = 0; g < 4; ++g) {
        oacc[g][0] = __builtin_amdgcn_mfma_f32_16x16x32_bf16(vc[0], bp[g][0], oacc[g][0], 0, 0, 0);
        oacc[g][1] = __builtin_amdgcn_mfma_f32_16x16x32_bf16(vc[1], bp[g][0], oacc[g][1], 0, 0, 0);
        oacc[g][2] = __builtin_amdgcn_mfma_f32_16x16x32_bf16(vc[2], bp[g][0], oacc[g][2], 0, 0, 0);
        oacc[g][3] = __builtin_amdgcn_mfma_f32_16x16x32_bf16(vc[3], bp[g][0], oacc[g][3], 0, 0, 0);
        oacc[g][0] = __builtin_amdgcn_mfma_f32_16x16x32_bf16(vc[4], bp[g][1], oacc[g][0], 0, 0, 0);
        oacc[g][1] = __builtin_amdgcn_mfma_f32_16x16x32_bf16(vc[5], bp[g][1], oacc[g][1], 0, 0, 0);
        oacc[g][2] = __builtin_amdgcn_mfma_f32_16x16x32_bf16(vc[6], bp[g][1], oacc[g][2], 0, 0, 0);
        oacc[g][3] = __builtin_amdgcn_mfma_f32_16x16x32_bf16(vc[7], bp[g][1], oacc[g][3], 0, 0, 0);
      }
      __builtin_amdgcn_s_setprio(0);

      kv0 += 256;
    }

    // ---- cross-wave combine (disjoint kv stripes -> plain f32 sums) ----
    // quad-reduce lp per group (all lanes end up with q=l15's total)
#pragma unroll
    for (int g = 0; g < 4; ++g) {
      lp[g] += __shfl_xor(lp[g], 16);
      lp[g] += __shfl_xor(lp[g], 32);
    }

    // write partials for groups this wave does NOT own
#pragma unroll
    for (int g = 0; g < 4; ++g) {
      if (g != w) {
        const int idx = (w < g) ? w : w - 1;
#pragma unroll
        for (int db = 0; db < 4; ++db)
          *(f32x4*)&Osum[g][idx][db][quad][l15][0] = oacc[g][db];
        if (lane < 16) Lsum[g][idx][l15] = lp[g];
      }
    }

    // extract own group's partial (static-index unroll; rule #20)
    f32x4 own[4];
    float lpo = 0.f;
#pragma unroll
    for (int g = 0; g < 4; ++g) {
      if (g == w) {
        own[0] = oacc[g][0]; own[1] = oacc[g][1];
        own[2] = oacc[g][2]; own[3] = oacc[g][3];
        lpo = lp[g];
      }
    }

    __syncthreads();

    // wave w combines + stores group w (q rows Q0 + w*16 .. +15)
    const float lt = lpo + Lsum[w][0][l15] + Lsum[w][1][l15] + Lsum[w][2][l15];
    const float il = 1.f / lt;
    const int qrow = Q0 + (w << 4) + l15;
    unsigned short* ob = Qio + ((size_t)(b * SEQL + qrow)) * DMODEL + h * DHEAD + quad * 4;
#pragma unroll
    for (int db = 0; db < 4; ++db) {
      f32x4 o = own[db];
      o += *(const f32x4*)&Osum[w][0][db][quad][l15][0];
      o += *(const f32x4*)&Osum[w][1][db][quad][l15][0];
      o += *(const f32x4*)&Osum[w][2][db][quad][l15][0];
      ushort4 v;
      v.x = f2bf(o[0] * il); v.y = f2bf(o[1] * il);
      v.z = f2bf(o[2] * il); v.w = f2bf(o[3] * il);
      *(ushort4*)(ob + db * 16) = v;
    }

    __syncthreads();   // protect LDS reuse by the next phase
  }
}

// ---------------------------------------------------------------------------
extern "C" void kernel_launch(void* const* d_in, const int* in_sizes, int n_in,
                              void* d_out, int out_size, void* d_ws, size_t ws_size,
                              hipStream_t stream) {
  (void)in_sizes; (void)n_in; (void)out_size; (void)ws_size;
  const float* x  = (const float*)d_in[0];
  const int* tpos = (const int*)d_in[1];
  const float* Wq = (const float*)d_in[2];
  const float* Wk = (const float*)d_in[3];
  const float* Wv = (const float*)d_in[4];
  const float* Wo = (const float*)d_in[5];
  float* out      = (float*)d_out;

  char* ws = (char*)d_ws;
  const size_t MB = 1024 * 1024;
  unsigned short* Qf  = (unsigned short*)(ws);            // 8 MB
  unsigned short* Kf  = (unsigned short*)(ws + 8 * MB);   // 8 MB
  unsigned short* Vt  = (unsigned short*)(ws + 16 * MB);  // 8 MB
  unsigned short* xb  = (unsigned short*)(ws + 24 * MB);  // 8 MB
  unsigned short* wqb = (unsigned short*)(ws + 32 * MB);  // 2 MB
  unsigned short* wkb = (unsigned short*)(ws + 34 * MB);  // 2 MB
  unsigned short* wvb = (unsigned short*)(ws + 36 * MB);  // 2 MB
  unsigned short* wob = (unsigned short*)(ws + 38 * MB);  // 2 MB -> 40 MB total

  // one-shot fp32 -> bf16 conversion (x + 4 weights)
  cvt_bf16<<<dim3(512, 8), 256, 0, stream>>>(x, Wq, Wk, Wv, Wo, xb, wqb, wkb, wvb, wob);
  // Q,K,V projections (all-bf16, async staging; V written transposed)
  gemm_qkv<<<dim3(8, 32, 3), 256, 0, stream>>>(xb, wqb, wkb, wvb, Qf, Kf, Vt, MROWS, DMODEL, DMODEL);
  // RoPE in place on Q,K (Q pre-scaled by 0.125)
  rope_inplace<<<dim3(MROWS), 256, 0, stream>>>(Qf, Kf, tpos);
  // causal attention; barrier-free kv-striped waves, 512 paired blocks
  attn_kernel<<<dim3(512), 256, 0, stream>>>(Kf, Vt, Qf);
  // output projection (bf16 A, bf16 W, fp32 out)
  gemm_out<<<dim3(8, 32, 1), 256, 0, stream>>>(Qf, wob, out, MROWS, DMODEL, DMODEL);
}

// Round 7
// 199.330 us; speedup vs baseline: 1.0914x; 1.0914x over previous
//
#include <hip/hip_runtime.h>
#include <cstdint>
#include <cstddef>

#define SEQL   2048
#define DMODEL 1024
#define NHEADS 16
#define DHEAD  64
#define MROWS  4096   // BATCH * SEQ

typedef __attribute__((ext_vector_type(8))) short short8;   // 8 bf16 (4 VGPRs)
typedef __attribute__((ext_vector_type(4))) float f32x4;    // MFMA 16x16 C/D

__device__ __forceinline__ unsigned short f2bf(float x) {
  unsigned int u = __float_as_uint(x);
  u += 0x7fffu + ((u >> 16) & 1u);   // round-to-nearest-even
  return (unsigned short)(u >> 16);
}
__device__ __forceinline__ float bf2f(unsigned short u) {
  return __uint_as_float(((unsigned int)u) << 16);
}
// load 8 contiguous fp32, round to 8 bf16
__device__ __forceinline__ short8 cvt8(const float* __restrict__ p) {
  const float4 lo = *(const float4*)p;
  const float4 hi = *(const float4*)(p + 4);
  short8 v;
  v[0] = (short)f2bf(lo.x); v[1] = (short)f2bf(lo.y);
  v[2] = (short)f2bf(lo.z); v[3] = (short)f2bf(lo.w);
  v[4] = (short)f2bf(hi.x); v[5] = (short)f2bf(hi.y);
  v[6] = (short)f2bf(hi.z); v[7] = (short)f2bf(hi.w);
  return v;
}
// async global->LDS, 16B per lane; lds base must be wave-uniform
__device__ __forceinline__ void gload_lds16(const unsigned short* g, unsigned short* l) {
  __builtin_amdgcn_global_load_lds(
      (const __attribute__((address_space(1))) unsigned int*)g,
      (__attribute__((address_space(3))) unsigned int*)l, 16, 0, 0);
}

// ---------------------------------------------------------------------------
// One-shot fp32 -> bf16 conversion of x and the four weight matrices.
// ---------------------------------------------------------------------------
__global__ __launch_bounds__(256) void cvt_bf16(
    const float* __restrict__ x,  const float* __restrict__ wq,
    const float* __restrict__ wk, const float* __restrict__ wv,
    const float* __restrict__ wo,
    unsigned short* __restrict__ xb,  unsigned short* __restrict__ wqb,
    unsigned short* __restrict__ wkb, unsigned short* __restrict__ wvb,
    unsigned short* __restrict__ wob) {
  const int y = blockIdx.y;
  const float* src; unsigned short* dst;
  if (y < 4)       { src = x + ((size_t)y << 20); dst = xb + ((size_t)y << 20); }
  else if (y == 4) { src = wq; dst = wqb; }
  else if (y == 5) { src = wk; dst = wkb; }
  else if (y == 6) { src = wv; dst = wvb; }
  else             { src = wo; dst = wob; }
  const size_t i = ((size_t)blockIdx.x * 256 + threadIdx.x) * 8;
  *(short8*)(dst + i) = cvt8(src + i);
}

// ---------------------------------------------------------------------------
// QKV projection, all-bf16, async staging (m97-style).
// z=0 -> Q bf16; z=1 -> K bf16; z=2 -> V transposed into Vt.
// ---------------------------------------------------------------------------
__global__ __launch_bounds__(256) void gemm_qkv(
    const unsigned short* __restrict__ A,
    const unsigned short* __restrict__ W0, const unsigned short* __restrict__ W1,
    const unsigned short* __restrict__ W2,
    unsigned short* __restrict__ C0, unsigned short* __restrict__ C1,
    unsigned short* __restrict__ Vt,
    int Mda, int Nda, int Kda) {
  const unsigned short* W;
  if (blockIdx.z == 0)      W = W0;
  else if (blockIdx.z == 1) W = W1;
  else                      W = W2;

  __shared__ __attribute__((aligned(16))) unsigned short As[128 * 32];
  __shared__ __attribute__((aligned(16))) unsigned short Bs[128 * 32];

  const int t = threadIdx.x;
  const int m0 = blockIdx.y * 128, n0 = blockIdx.x * 128;
  const int w = t >> 6, lane = t & 63;
  const int l15 = lane & 15, quad = lane >> 4;
  const int wm = (w >> 1) * 64, wn = (w & 1) * 64;

  const int r1 = t >> 2,         c1 = (t & 3) * 8;
  const int r2 = (t + 256) >> 2, c2 = (t & 3) * 8;
  unsigned short* asd1 = As + (size_t)(w << 6) * 8;
  unsigned short* asd2 = As + (size_t)(256 + (w << 6)) * 8;
  unsigned short* bsd1 = Bs + (size_t)(w << 6) * 8;
  unsigned short* bsd2 = Bs + (size_t)(256 + (w << 6)) * 8;

  f32x4 acc[4][4] = {};

  for (int k0 = 0; k0 < Kda; k0 += 32) {
    __syncthreads();
    gload_lds16(A + (size_t)(m0 + r1) * Kda + k0 + c1, asd1);
    gload_lds16(A + (size_t)(m0 + r2) * Kda + k0 + c2, asd2);
    gload_lds16(W + (size_t)(n0 + r1) * Kda + k0 + c1, bsd1);
    gload_lds16(W + (size_t)(n0 + r2) * Kda + k0 + c2, bsd2);
    __syncthreads();

    short8 af[4], bfr[4];
#pragma unroll
    for (int i = 0; i < 4; ++i)
      af[i] = *(const short8*)(&As[(wm + i * 16 + l15) * 32 + quad * 8]);
#pragma unroll
    for (int j = 0; j < 4; ++j)
      bfr[j] = *(const short8*)(&Bs[(wn + j * 16 + l15) * 32 + quad * 8]);
#pragma unroll
    for (int i = 0; i < 4; ++i)
#pragma unroll
      for (int j = 0; j < 4; ++j)
        acc[i][j] = __builtin_amdgcn_mfma_f32_16x16x32_bf16(af[i], bfr[j], acc[i][j], 0, 0, 0);
  }

  if (blockIdx.z != 2) {
    unsigned short* C = (blockIdx.z == 0) ? C0 : C1;
#pragma unroll
    for (int i = 0; i < 4; ++i)
#pragma unroll
      for (int j = 0; j < 4; ++j)
#pragma unroll
        for (int r = 0; r < 4; ++r) {
          int row = m0 + wm + i * 16 + quad * 4 + r;
          int col = n0 + wn + j * 16 + l15;
          C[(size_t)row * Nda + col] = f2bf(acc[i][j][r]);
        }
  } else {
    // V transposed write: 4 consecutive s-values per 8B store
#pragma unroll
    for (int i = 0; i < 4; ++i) {
      const int srow = m0 + wm + i * 16 + quad * 4;   // b*SEQL + s (s%4==0)
      const int bq = srow >> 11, s = srow & (SEQL - 1);
#pragma unroll
      for (int j = 0; j < 4; ++j) {
        const int col = n0 + wn + j * 16 + l15;       // h*64 + d
        ushort4 v;
        v.x = f2bf(acc[i][j][0]); v.y = f2bf(acc[i][j][1]);
        v.z = f2bf(acc[i][j][2]); v.w = f2bf(acc[i][j][3]);
        *(ushort4*)(Vt + ((size_t)(bq * DMODEL + col)) * SEQL + s) = v;
      }
    }
  }
}

// ---------------------------------------------------------------------------
// Output projection: A bf16 [M][K], W bf16 [N][K], C fp32 [M][N]
// ---------------------------------------------------------------------------
__global__ __launch_bounds__(256) void gemm_out(
    const unsigned short* __restrict__ A,
    const unsigned short* __restrict__ W,
    float* __restrict__ C,
    int Mda, int Nda, int Kda) {
  __shared__ __attribute__((aligned(16))) unsigned short As[128 * 32];
  __shared__ __attribute__((aligned(16))) unsigned short Bs[128 * 32];

  const int t = threadIdx.x;
  const int m0 = blockIdx.y * 128, n0 = blockIdx.x * 128;
  const int w = t >> 6, lane = t & 63;
  const int l15 = lane & 15, quad = lane >> 4;
  const int wm = (w >> 1) * 64, wn = (w & 1) * 64;

  const int r1 = t >> 2,         c1 = (t & 3) * 8;
  const int r2 = (t + 256) >> 2, c2 = (t & 3) * 8;
  unsigned short* asd1 = As + (size_t)(w << 6) * 8;
  unsigned short* asd2 = As + (size_t)(256 + (w << 6)) * 8;
  unsigned short* bsd1 = Bs + (size_t)(w << 6) * 8;
  unsigned short* bsd2 = Bs + (size_t)(256 + (w << 6)) * 8;

  f32x4 acc[4][4] = {};

  for (int k0 = 0; k0 < Kda; k0 += 32) {
    __syncthreads();
    gload_lds16(A + (size_t)(m0 + r1) * Kda + k0 + c1, asd1);
    gload_lds16(A + (size_t)(m0 + r2) * Kda + k0 + c2, asd2);
    gload_lds16(W + (size_t)(n0 + r1) * Kda + k0 + c1, bsd1);
    gload_lds16(W + (size_t)(n0 + r2) * Kda + k0 + c2, bsd2);
    __syncthreads();

    short8 af[4], bfr[4];
#pragma unroll
    for (int i = 0; i < 4; ++i)
      af[i] = *(const short8*)(&As[(wm + i * 16 + l15) * 32 + quad * 8]);
#pragma unroll
    for (int j = 0; j < 4; ++j)
      bfr[j] = *(const short8*)(&Bs[(wn + j * 16 + l15) * 32 + quad * 8]);
#pragma unroll
    for (int i = 0; i < 4; ++i)
#pragma unroll
      for (int j = 0; j < 4; ++j)
        acc[i][j] = __builtin_amdgcn_mfma_f32_16x16x32_bf16(af[i], bfr[j], acc[i][j], 0, 0, 0);
  }

#pragma unroll
  for (int i = 0; i < 4; ++i)
#pragma unroll
    for (int j = 0; j < 4; ++j)
#pragma unroll
      for (int r = 0; r < 4; ++r) {
        int row = m0 + wm + i * 16 + quad * 4 + r;
        int col = n0 + wn + j * 16 + l15;
        C[(size_t)row * Nda + col] = acc[i][j][r];
      }
}

// ---------------------------------------------------------------------------
// In-place RoPE on bf16 Q and K flat [M][1024].  R17: table-in-LDS.
// Old version: EVERY thread ran exp2f+sincosf (2M transcendentals total) ->
// VALU-bound (guide m205). New: 32 threads/block compute the 32 (cos,sin)
// pairs once into LDS (sincosf count /16); all 256 threads then do pure
// vectorized ushort4 rotate at HBM BW. Same sincosf/exp2f on same inputs ->
// identical rounding. Q additionally pre-scaled by 0.125 (exact in bf16).
// ---------------------------------------------------------------------------
__global__ __launch_bounds__(256) void rope_inplace(unsigned short* __restrict__ Q,
                                                    unsigned short* __restrict__ K,
                                                    const int* __restrict__ pos_arr) {
  __shared__ float cs[32], sn[32];
  const int row = blockIdx.x;            // b*SEQ + s
  const int s = row & (SEQL - 1);
  const int t = threadIdx.x;
  if (t < 32) {
    const float pos = (float)pos_arr[s];
    // log2(10000)/32 = 0.4152410118609203
    const float inv = exp2f((float)t * -0.4152410118609203f);
    const float ang = pos * inv;
    float ss, cc;
    sincosf(ang, &ss, &cc);
    cs[t] = cc; sn[t] = ss;
  }
  __syncthreads();

  // thread t handles head h = t>>4, pairs i0 = (t&15)*2 and i0+1 (4 shorts)
  const int i0 = (t & 15) * 2;
  const size_t base = (size_t)row * DMODEL + (size_t)(t >> 4) * DHEAD + (size_t)i0 * 2;
  const float c0 = cs[i0], s0 = sn[i0];
  const float c1 = cs[i0 + 1], s1 = sn[i0 + 1];

  ushort4 q = *(const ushort4*)(Q + base);
  ushort4 k = *(const ushort4*)(K + base);
  ushort4 r;
  float e, o;
  e = bf2f(q.x); o = bf2f(q.y);
  r.x = f2bf((e * c0 - o * s0) * 0.125f);
  r.y = f2bf((e * s0 + o * c0) * 0.125f);
  e = bf2f(q.z); o = bf2f(q.w);
  r.z = f2bf((e * c1 - o * s1) * 0.125f);
  r.w = f2bf((e * s1 + o * c1) * 0.125f);
  *(ushort4*)(Q + base) = r;

  e = bf2f(k.x); o = bf2f(k.y);
  r.x = f2bf(e * c0 - o * s0);
  r.y = f2bf(e * s0 + o * c0);
  e = bf2f(k.z); o = bf2f(k.w);
  r.z = f2bf(e * c1 - o * s1);
  r.w = f2bf(e * s1 + o * c1);
  *(ushort4*)(K + base) = r;
}

// ---------------------------------------------------------------------------
// Causal attention — PROVEN R0 version (46.8us, VGPR 44, no spills).
// R5-verified transposed-MFMA math, 2-barrier DMA staging, kv64 tiles,
// light/heavy pairing (qblk p then 31-p -> uniform 33 trips), 512 blocks =
// exactly 2 resident/CU, XCD-swizzled bh, wave-uniform fast path.
// R16's barrier-free variant spilled (VGPR demand > budget -> 36MB scratch
// writes); reverted.
// ---------------------------------------------------------------------------
__global__ __launch_bounds__(256, 2) void attn_kernel(const unsigned short* __restrict__ Kf,
                                                      const unsigned short* __restrict__ Vt,
                                                      unsigned short* __restrict__ Qio) {
  __shared__ __attribute__((aligned(16))) unsigned short Ks[4096];  // 8 KB: kv64 x d64
  __shared__ __attribute__((aligned(16))) unsigned short Vs[4096];  // 8 KB: d64 x kv64

  const int id = blockIdx.x;                    // id = grp*128 + qpair*8 + xcd
  const int bh = ((id >> 7) << 3) | (id & 7);   // grp*8 + xcd (L2 locality)
  const int qpair = (id >> 3) & 15;             // 0..15
  const int b = bh >> 4, h = bh & 15;
  const int w = threadIdx.x >> 6;
  const int lane = threadIdx.x & 63;
  const int l15 = lane & 15, quad = lane >> 4;

  // staging source addresses (lane-permuted so LDS slot = fragment layout)
  const int g = (w << 6) | lane;
  const int ktau = g >> 7, kseg = (g >> 4) & 7, km = g & 15;
  const int kvl = 8 * (km >> 2) + (km & 3) + 4 * ktau;
  const unsigned short* kstage = Kf + ((size_t)(b * SEQL + kvl)) * DMODEL + h * DHEAD + kseg * 8;
  const int vdb = (g >> 6) & 3, vq = (g >> 4) & 3, vm = g & 15;
  const unsigned short* vstage = Vt + ((size_t)(bh * DHEAD + vdb * 16 + vm)) * SEQL + vq * 8;
  unsigned short* kdst0 = Ks + (size_t)(w << 6) * 8;          // kv 0..31 half
  unsigned short* kdst1 = Ks + 2048 + (size_t)(w << 6) * 8;   // kv 32..63 half
  unsigned short* vdst0 = Vs + (size_t)(w << 6) * 8;
  unsigned short* vdst1 = Vs + 2048 + (size_t)(w << 6) * 8;

  // fragment read offset (shorts) within a 2048-short half
  const int rs = (l15 + (quad << 4)) << 3;

#pragma unroll 1
  for (int phase = 0; phase < 2; ++phase) {
    const int qblk = (phase == 0) ? qpair : 31 - qpair;
    const int qw = qblk * 64 + w * 16;
    const int qrow = qw + l15;

    // Q B-frag: n=l15 (q), k=8*quad+j (d)
    const unsigned short* qp = Qio + ((size_t)(b * SEQL + qrow)) * DMODEL + h * DHEAD + quad * 8;
    const short8 bq0 = *(const short8*)(qp);
    const short8 bq1 = *(const short8*)(qp + 32);

    f32x4 oa0 = {0.f, 0.f, 0.f, 0.f}, oa1 = oa0, oa2 = oa0, oa3 = oa0;
    float lp = 0.f;

    const int trips = qblk + 1;   // kv64 tiles; block-uniform
    for (int t = 0; t < trips; ++t) {
      const int kv0 = t * 64;
      __syncthreads();   // all waves done reading previous tile
      gload_lds16(kstage + (size_t)kv0 * DMODEL, kdst0);
      gload_lds16(kstage + (size_t)(kv0 + 32) * DMODEL, kdst1);
      gload_lds16(vstage + kv0, vdst0);
      gload_lds16(vstage + kv0 + 32, vdst1);
      __syncthreads();   // staged data visible

      // QK^T: 4 score accumulators (kv groups +0, +4, +32, +36)
      const short8 ak10 = *(const short8*)(Ks + rs);
      const short8 ak11 = *(const short8*)(Ks + rs + 512);
      const short8 ak20 = *(const short8*)(Ks + rs + 1024);
      const short8 ak21 = *(const short8*)(Ks + rs + 1536);
      const short8 ak30 = *(const short8*)(Ks + 2048 + rs);
      const short8 ak31 = *(const short8*)(Ks + 2048 + rs + 512);
      const short8 ak40 = *(const short8*)(Ks + 2048 + rs + 1024);
      const short8 ak41 = *(const short8*)(Ks + 2048 + rs + 1536);
      f32x4 z = {0.f, 0.f, 0.f, 0.f};
      f32x4 s1 = __builtin_amdgcn_mfma_f32_16x16x32_bf16(ak10, bq0, z, 0, 0, 0);
      s1 = __builtin_amdgcn_mfma_f32_16x16x32_bf16(ak11, bq1, s1, 0, 0, 0);
      f32x4 s2 = __builtin_amdgcn_mfma_f32_16x16x32_bf16(ak20, bq0, z, 0, 0, 0);
      s2 = __builtin_amdgcn_mfma_f32_16x16x32_bf16(ak21, bq1, s2, 0, 0, 0);
      f32x4 s3 = __builtin_amdgcn_mfma_f32_16x16x32_bf16(ak30, bq0, z, 0, 0, 0);
      s3 = __builtin_amdgcn_mfma_f32_16x16x32_bf16(ak31, bq1, s3, 0, 0, 0);
      f32x4 s4 = __builtin_amdgcn_mfma_f32_16x16x32_bf16(ak40, bq0, z, 0, 0, 0);
      s4 = __builtin_amdgcn_mfma_f32_16x16x32_bf16(ak41, bq1, s4, 0, 0, 0);

      // exp (+causal mask on the last trip per wave) -> PV B-operands
      short8 bp0, bp1;
      if (kv0 + 63 <= qw) {   // wave-uniform fast path: no masking needed
#pragma unroll
        for (int r = 0; r < 4; ++r) {
          const float p1 = __expf(s1[r]);
          const float p2 = __expf(s2[r]);
          const float p3 = __expf(s3[r]);
          const float p4 = __expf(s4[r]);
          lp += (p1 + p2) + (p3 + p4);
          bp0[r]     = (short)f2bf(p1);
          bp0[4 + r] = (short)f2bf(p2);
          bp1[r]     = (short)f2bf(p3);
          bp1[4 + r] = (short)f2bf(p4);
        }
      } else {
#pragma unroll
        for (int r = 0; r < 4; ++r) {
          const int kv1 = kv0 + 8 * quad + r;
          const float p1 = (kv1 > qrow)      ? 0.f : __expf(s1[r]);
          const float p2 = (kv1 + 4 > qrow)  ? 0.f : __expf(s2[r]);
          const float p3 = (kv1 + 32 > qrow) ? 0.f : __expf(s3[r]);
          const float p4 = (kv1 + 36 > qrow) ? 0.f : __expf(s4[r]);
          lp += (p1 + p2) + (p3 + p4);
          bp0[r]     = (short)f2bf(p1);
          bp0[4 + r] = (short)f2bf(p2);
          bp1[r]     = (short)f2bf(p3);
          bp1[4 + r] = (short)f2bf(p4);
        }
      }

      // PV: A = V^T frags (d-block x kv-half), B = bp
      const short8 av0l = *(const short8*)(Vs + rs);
      const short8 av1l = *(const short8*)(Vs + rs + 512);
      const short8 av2l = *(const short8*)(Vs + rs + 1024);
      const short8 av3l = *(const short8*)(Vs + rs + 1536);
      const short8 av0h = *(const short8*)(Vs + 2048 + rs);
      const short8 av1h = *(const short8*)(Vs + 2048 + rs + 512);
      const short8 av2h = *(const short8*)(Vs + 2048 + rs + 1024);
      const short8 av3h = *(const short8*)(Vs + 2048 + rs + 1536);
      oa0 = __builtin_amdgcn_mfma_f32_16x16x32_bf16(av0l, bp0, oa0, 0, 0, 0);
      oa1 = __builtin_amdgcn_mfma_f32_16x16x32_bf16(av1l, bp0, oa1, 0, 0, 0);
      oa2 = __builtin_amdgcn_mfma_f32_16x16x32_bf16(av2l, bp0, oa2, 0, 0, 0);
      oa3 = __builtin_amdgcn_mfma_f32_16x16x32_bf16(av3l, bp0, oa3, 0, 0, 0);
      oa0 = __builtin_amdgcn_mfma_f32_16x16x32_bf16(av0h, bp1, oa0, 0, 0, 0);
      oa1 = __builtin_amdgcn_mfma_f32_16x16x32_bf16(av1h, bp1, oa1, 0, 0, 0);
      oa2 = __builtin_amdgcn_mfma_f32_16x16x32_bf16(av2h, bp1, oa2, 0, 0, 0);
      oa3 = __builtin_amdgcn_mfma_f32_16x16x32_bf16(av3h, bp1, oa3, 0, 0, 0);
    }

    // reduce row sum across the 4 quads holding this q's kv slices
    lp += __shfl_xor(lp, 16);
    lp += __shfl_xor(lp, 32);
    const float il = 1.f / lp;

    // O^T: lane holds q=l15's d = db*16 + 4*quad + r  -> 4x ushort4 stores
    unsigned short* ob = Qio + ((size_t)(b * SEQL + qrow)) * DMODEL + h * DHEAD + quad * 4;
    {
      ushort4 v;
      v.x = f2bf(oa0[0] * il); v.y = f2bf(oa0[1] * il);
      v.z = f2bf(oa0[2] * il); v.w = f2bf(oa0[3] * il);
      *(ushort4*)(ob) = v;
      v.x = f2bf(oa1[0] * il); v.y = f2bf(oa1[1] * il);
      v.z = f2bf(oa1[2] * il); v.w = f2bf(oa1[3] * il);
      *(ushort4*)(ob + 16) = v;
      v.x = f2bf(oa2[0] * il); v.y = f2bf(oa2[1] * il);
      v.z = f2bf(oa2[2] * il); v.w = f2bf(oa2[3] * il);
      *(ushort4*)(ob + 32) = v;
      v.x = f2bf(oa3[0] * il); v.y = f2bf(oa3[1] * il);
      v.z = f2bf(oa3[2] * il); v.w = f2bf(oa3[3] * il);
      *(ushort4*)(ob + 48) = v;
    }
  }
}

// ---------------------------------------------------------------------------
extern "C" void kernel_launch(void* const* d_in, const int* in_sizes, int n_in,
                              void* d_out, int out_size, void* d_ws, size_t ws_size,
                              hipStream_t stream) {
  (void)in_sizes; (void)n_in; (void)out_size; (void)ws_size;
  const float* x  = (const float*)d_in[0];
  const int* tpos = (const int*)d_in[1];
  const float* Wq = (const float*)d_in[2];
  const float* Wk = (const float*)d_in[3];
  const float* Wv = (const float*)d_in[4];
  const float* Wo = (const float*)d_in[5];
  float* out      = (float*)d_out;

  char* ws = (char*)d_ws;
  const size_t MB = 1024 * 1024;
  unsigned short* Qf  = (unsigned short*)(ws);            // 8 MB
  unsigned short* Kf  = (unsigned short*)(ws + 8 * MB);   // 8 MB
  unsigned short* Vt  = (unsigned short*)(ws + 16 * MB);  // 8 MB
  unsigned short* xb  = (unsigned short*)(ws + 24 * MB);  // 8 MB
  unsigned short* wqb = (unsigned short*)(ws + 32 * MB);  // 2 MB
  unsigned short* wkb = (unsigned short*)(ws + 34 * MB);  // 2 MB
  unsigned short* wvb = (unsigned short*)(ws + 36 * MB);  // 2 MB
  unsigned short* wob = (unsigned short*)(ws + 38 * MB);  // 2 MB -> 40 MB total

  // one-shot fp32 -> bf16 conversion (x + 4 weights)
  cvt_bf16<<<dim3(512, 8), 256, 0, stream>>>(x, Wq, Wk, Wv, Wo, xb, wqb, wkb, wvb, wob);
  // Q,K,V projections (all-bf16, async staging; V written transposed)
  gemm_qkv<<<dim3(8, 32, 3), 256, 0, stream>>>(xb, wqb, wkb, wvb, Qf, Kf, Vt, MROWS, DMODEL, DMODEL);
  // RoPE in place on Q,K (table-in-LDS; Q pre-scaled by 0.125)
  rope_inplace<<<dim3(MROWS), 256, 0, stream>>>(Qf, Kf, tpos);
  // causal attention; 512 paired blocks (uniform 33 trips), XCD-swizzled
  attn_kernel<<<dim3(512), 256, 0, stream>>>(Kf, Vt, Qf);
  // output projection (bf16 A, bf16 W, fp32 out)
  gemm_out<<<dim3(8, 32, 1), 256, 0, stream>>>(Qf, wob, out, MROWS, DMODEL, DMODEL);
}